// Round 1
// baseline (338.494 us; speedup 1.0000x reference)
//
#include <hip/hip_runtime.h>

// CutMix: out[b,h,w,c] = inside_box(b,h,w) ? x[perm[b],h,w,c] : x[b,h,w,c]
// B=64, H=512, W=512, C=3, float32. Pure memory-bound elementwise select.

constexpr unsigned Bn  = 64;
constexpr unsigned Hn  = 512;
constexpr unsigned Wn  = 512;
constexpr unsigned Cn  = 3;
constexpr unsigned WC    = Wn * Cn;      // 1536 floats per row (divisible by 4)
constexpr unsigned HWC   = Hn * WC;      // 786432 floats per image
constexpr unsigned HWC4  = HWC / 4;      // 196608 float4 per image
constexpr unsigned TOTAL4 = Bn * HWC4;   // 12582912 float4 total

__global__ __launch_bounds__(256) void cutmix_kernel(
    const float4* __restrict__ x,
    const int* __restrict__ y1v, const int* __restrict__ y2v,
    const int* __restrict__ x1v, const int* __restrict__ x2v,
    const int* __restrict__ permv,
    float4* __restrict__ out)
{
    const unsigned i = blockIdx.x * 256u + threadIdx.x;   // float4 index
    const unsigned b  = i / HWC4;
    const unsigned ri = i - b * HWC4;      // float4 index within image
    const unsigned r  = ri * 4u;           // element index within image
    const unsigned h  = r / WC;
    const unsigned r2 = r - h * WC;        // element index within row

    const int yy1 = y1v[b], yy2 = y2v[b];
    const bool inside_h = ((int)h >= yy1) && ((int)h < yy2);

    bool in0 = false, in1 = false, in2 = false, in3 = false;
    if (inside_h) {
        const int xx1 = x1v[b], xx2 = x2v[b];
        const int w0 = (int)( r2        / 3u);
        const int w1 = (int)((r2 + 1u)  / 3u);
        const int w2 = (int)((r2 + 2u)  / 3u);
        const int w3 = (int)((r2 + 3u)  / 3u);
        in0 = (w0 >= xx1) && (w0 < xx2);
        in1 = (w1 >= xx1) && (w1 < xx2);
        in2 = (w2 >= xx1) && (w2 < xx2);
        in3 = (w3 >= xx1) && (w3 < xx2);
    }

    float4 v;
    if (in0 & in1 & in2 & in3) {
        // fully inside the box: read only the shuffled image
        const unsigned pb = (unsigned)permv[b];
        v = x[pb * HWC4 + ri];
    } else if (!(in0 | in1 | in2 | in3)) {
        // fully outside: read only own image
        v = x[i];
    } else {
        // box boundary within this float4: blend per element
        const float4 xv = x[i];
        const unsigned pb = (unsigned)permv[b];
        const float4 sv = x[pb * HWC4 + ri];
        v.x = in0 ? sv.x : xv.x;
        v.y = in1 ? sv.y : xv.y;
        v.z = in2 ? sv.z : xv.z;
        v.w = in3 ? sv.w : xv.w;
    }
    out[i] = v;
}

extern "C" void kernel_launch(void* const* d_in, const int* in_sizes, int n_in,
                              void* d_out, int out_size, void* d_ws, size_t ws_size,
                              hipStream_t stream) {
    const float4* x   = (const float4*)d_in[0];
    const int* y1v    = (const int*)d_in[1];
    const int* y2v    = (const int*)d_in[2];
    const int* x1v    = (const int*)d_in[3];
    const int* x2v    = (const int*)d_in[4];
    const int* permv  = (const int*)d_in[5];
    float4* out       = (float4*)d_out;

    cutmix_kernel<<<TOTAL4 / 256u, 256, 0, stream>>>(x, y1v, y2v, x1v, x2v, permv, out);
}

// Round 3
// 328.295 us; speedup vs baseline: 1.0311x; 1.0311x over previous
//
#include <hip/hip_runtime.h>

// CutMix: out[b,h,w,c] = inside_box(b,h,w) ? x[perm[b],h,w,c] : x[b,h,w,c]
// B=64, H=512, W=512, C=3, float32. Pure memory-bound elementwise select.
//
// Layout trick: one block == one image row. Row = W*C = 1536 floats = 384
// float4 = one 384-thread block (6 waves). So b/h are wave-uniform scalars,
// box params are s_loads, and rows outside [y1,y2) take a uniform branch to
// a pure streaming copy.
//
// Use a native ext_vector float4 — __builtin_nontemporal_store rejects
// HIP's class-type float4.
typedef float f4 __attribute__((ext_vector_type(4)));

constexpr unsigned Bn  = 64;
constexpr unsigned Hn  = 512;
constexpr unsigned Wn  = 512;
constexpr unsigned Cn  = 3;
constexpr unsigned WC   = Wn * Cn;     // 1536 floats per row
constexpr unsigned WC4  = WC / 4;      // 384 float4 per row
constexpr unsigned HWC4 = Hn * WC4;    // 196608 float4 per image

__global__ __launch_bounds__(384) void cutmix_kernel(
    const f4* __restrict__ x,
    const int* __restrict__ y1v, const int* __restrict__ y2v,
    const int* __restrict__ x1v, const int* __restrict__ x2v,
    const int* __restrict__ permv,
    f4* __restrict__ out)
{
    const unsigned blk = blockIdx.x;
    const unsigned b   = blk >> 9;          // / 512  (wave-uniform)
    const unsigned h   = blk & 511u;        // % 512  (wave-uniform)
    const unsigned tid = threadIdx.x;
    const unsigned idx = b * HWC4 + h * WC4 + tid;   // float4 index

    const int yy1 = y1v[b];
    const int yy2 = y2v[b];

    if ((int)h >= yy1 && (int)h < yy2) {
        // row intersects the box
        const int xx1 = x1v[b];
        const int xx2 = x2v[b];
        const unsigned pb = (unsigned)permv[b];
        const unsigned pidx = pb * HWC4 + h * WC4 + tid;

        const unsigned e = tid * 4u;            // element offset within row
        const int w0 = (int)( e        / 3u);
        const int w1 = (int)((e + 1u)  / 3u);
        const int w2 = (int)((e + 2u)  / 3u);
        const int w3 = (int)((e + 3u)  / 3u);
        const bool in0 = (w0 >= xx1) && (w0 < xx2);
        const bool in1 = (w1 >= xx1) && (w1 < xx2);
        const bool in2 = (w2 >= xx1) && (w2 < xx2);
        const bool in3 = (w3 >= xx1) && (w3 < xx2);

        f4 v;
        if (in0 & in3) {
            // fully inside the box (w monotone within float4): shuffled image
            v = x[pidx];
        } else if (!(in0 | in3)) {
            // fully outside: own image
            v = x[idx];
        } else {
            // box edge crosses this float4: blend per element
            const f4 xv = x[idx];
            const f4 sv = x[pidx];
            v.x = in0 ? sv.x : xv.x;
            v.y = in1 ? sv.y : xv.y;
            v.z = in2 ? sv.z : xv.z;
            v.w = in3 ? sv.w : xv.w;
        }
        __builtin_nontemporal_store(v, &out[idx]);
    } else {
        // row entirely outside the box: streaming copy
        __builtin_nontemporal_store(x[idx], &out[idx]);
    }
}

extern "C" void kernel_launch(void* const* d_in, const int* in_sizes, int n_in,
                              void* d_out, int out_size, void* d_ws, size_t ws_size,
                              hipStream_t stream) {
    const f4* x       = (const f4*)d_in[0];
    const int* y1v    = (const int*)d_in[1];
    const int* y2v    = (const int*)d_in[2];
    const int* x1v    = (const int*)d_in[3];
    const int* x2v    = (const int*)d_in[4];
    const int* permv  = (const int*)d_in[5];
    f4* out           = (f4*)d_out;

    cutmix_kernel<<<Bn * Hn, 384, 0, stream>>>(x, y1v, y2v, x1v, x2v, permv, out);
}